// Round 2
// 1526.153 us; speedup vs baseline: 1.1877x; 1.1877x over previous
//
#include <hip/hip_runtime.h>

// SimpleRNN: h_{t+1} = tanh(h Wh^T + x_t Wx^T + b), return h_1024.
// SEQ=1024, NB=64, HID=512, IN=512. W is [512][1024] = [Wh | Wx]. All fp32 I/O.
//
// Phase 1 (prepass): U[t][b][j] = x_t[b]·Wx[j] + b[j] as MFMA f16 GEMM, U f16 in ws.
// Phase 2 (recurrent): 256 WGs = 64 batches x 4 row-slices, 1 WG/CU (coop).
//   R2: Wh slice lives in VGPRs (f16x8 wreg[32] = 128 VGPRs/thread, compile-time
//   indices only), not LDS -- kills the 131 KB/step LDS streaming (~1200 cy/step)
//   and the 2.9e7 bank-conflict cycles of the R0 kernel. Lane map: c=l&7 is the
//   k-chunk (64 ks), jj=l>>3 row group (4 rows); per-row partials live in lanes
//   differing in bits 0..2 -> 3-step shfl_xor butterfly replaces the serial
//   part[]/tid<64 reduce. h staged in LDS with 144 B chunk stride (bank-clean).
// Sync: identical to the verified R0 scheme -- every thread polls its word of
//   the parity ping-pong hbuf (atomic u64 {tag, 2xf16}); publish is hoisted
//   before SYNC2 (safe: publish(t+1) follows SYNC1(t), which proves all remote
//   slices reached tag t, which proves every remote WG finished reading tag t-1
//   before its slot is overwritten -- the 2-deep parity argument).

#define SEQ 1024
#define NB  64
#define HID 512

typedef _Float16 half2v __attribute__((ext_vector_type(2)));
typedef _Float16 f16x8  __attribute__((ext_vector_type(8)));
typedef float    f32x4  __attribute__((ext_vector_type(4)));

#if __has_builtin(__builtin_amdgcn_fdot2)
#define DOT2(a, b, c) __builtin_amdgcn_fdot2((a), (b), (c), false)
#else
static __device__ __forceinline__ float DOT2(half2v a, half2v b, float c) {
  return c + (float)a.x * (float)b.x + (float)a.y * (float)b.y;
}
#endif

static __device__ __forceinline__ float fast_tanh(float x) {
  // tanh(x) = (e^{2x}-1)/(e^{2x}+1); __expf -> v_exp_f32, err << f16 quantization
  float e = __expf(2.0f * x);
  return (e - 1.0f) / (e + 1.0f);
}

// ---------------------------------------------------------------- prepass ---
__global__ __launch_bounds__(256, 2)
void rnn_prepass(const float* __restrict__ X, const float* __restrict__ W,
                 const float* __restrict__ bias, _Float16* __restrict__ U) {
  __shared__ __align__(16) _Float16 As[128][40];  // +8 pad: bank-friendly
  __shared__ __align__(16) _Float16 Bs[128][40];
  const int tid = threadIdx.x;
  const int m0 = blockIdx.x * 128;   // 512 m-tiles
  const int n0 = blockIdx.y * 128;   // 4 n-tiles
  const int wave = tid >> 6, lane = tid & 63;
  const int wm = (wave >> 1) * 64, wn = (wave & 1) * 64;  // 2x2 wave grid
  const int l15 = lane & 15, q = lane >> 4;

  f32x4 acc[4][4];
#pragma unroll
  for (int i = 0; i < 4; ++i)
#pragma unroll
    for (int j = 0; j < 4; ++j) acc[i][j] = (f32x4){0.f, 0.f, 0.f, 0.f};

  const int srow = tid >> 1;
  const int shalf = (tid & 1) * 16;

  for (int k0 = 0; k0 < 512; k0 += 32) {
    const float* asrc = X + (size_t)(m0 + srow) * 512 + k0 + shalf;
    const float* bsrc = W + (size_t)(n0 + srow) * 1024 + 512 + k0 + shalf;
    float4 a0 = *(const float4*)(asrc);
    float4 a1 = *(const float4*)(asrc + 4);
    float4 a2 = *(const float4*)(asrc + 8);
    float4 a3 = *(const float4*)(asrc + 12);
    float4 b0 = *(const float4*)(bsrc);
    float4 b1 = *(const float4*)(bsrc + 4);
    float4 b2 = *(const float4*)(bsrc + 8);
    float4 b3 = *(const float4*)(bsrc + 12);
    __syncthreads();  // previous iter's frag reads done before LDS overwrite
    f16x8 pa0 = {(_Float16)a0.x, (_Float16)a0.y, (_Float16)a0.z, (_Float16)a0.w,
                 (_Float16)a1.x, (_Float16)a1.y, (_Float16)a1.z, (_Float16)a1.w};
    f16x8 pa1 = {(_Float16)a2.x, (_Float16)a2.y, (_Float16)a2.z, (_Float16)a2.w,
                 (_Float16)a3.x, (_Float16)a3.y, (_Float16)a3.z, (_Float16)a3.w};
    f16x8 pb0 = {(_Float16)b0.x, (_Float16)b0.y, (_Float16)b0.z, (_Float16)b0.w,
                 (_Float16)b1.x, (_Float16)b1.y, (_Float16)b1.z, (_Float16)b1.w};
    f16x8 pb1 = {(_Float16)b2.x, (_Float16)b2.y, (_Float16)b2.z, (_Float16)b2.w,
                 (_Float16)b3.x, (_Float16)b3.y, (_Float16)b3.z, (_Float16)b3.w};
    *(f16x8*)&As[srow][shalf] = pa0;
    *(f16x8*)&As[srow][shalf + 8] = pa1;
    *(f16x8*)&Bs[srow][shalf] = pb0;
    *(f16x8*)&Bs[srow][shalf + 8] = pb1;
    __syncthreads();
    f16x8 av[4], bv[4];
#pragma unroll
    for (int i = 0; i < 4; ++i)
      av[i] = *(const f16x8*)&As[wm + i * 16 + l15][q * 8];
#pragma unroll
    for (int j = 0; j < 4; ++j)
      bv[j] = *(const f16x8*)&Bs[wn + j * 16 + l15][q * 8];
#pragma unroll
    for (int i = 0; i < 4; ++i)
#pragma unroll
      for (int j = 0; j < 4; ++j)
        acc[i][j] = __builtin_amdgcn_mfma_f32_16x16x32_f16(av[i], bv[j], acc[i][j], 0, 0, 0);
  }
  float bj[4];
#pragma unroll
  for (int j = 0; j < 4; ++j) bj[j] = bias[n0 + wn + j * 16 + l15];
#pragma unroll
  for (int i = 0; i < 4; ++i)
#pragma unroll
    for (int j = 0; j < 4; ++j)
#pragma unroll
      for (int r = 0; r < 4; ++r) {
        // C/D layout: col = lane&15, row = (lane>>4)*4 + reg  [m89/m91]
        int m = m0 + wm + i * 16 + q * 4 + r;
        int n = n0 + wn + j * 16 + l15;
        U[(size_t)m * 512 + n] = (_Float16)(acc[i][j][r] + bj[j]);
      }
}

// -------------------------------------------------------------- recurrent ---
__global__ __launch_bounds__(256, 1)
void rnn_recur(const float* __restrict__ W, const _Float16* __restrict__ U,
               unsigned long long* hbuf, float* __restrict__ out) {
  const int blk = blockIdx.x;
  const int batch = blk & 63;
  const int g = blk >> 6;      // row-slice 0..3 (rows 128g..128g+127)
  const int tid = threadIdx.x;
  const int wvi = tid >> 6;    // wave 0..3
  const int l   = tid & 63;
  const int jj  = l >> 3;      // row group within wave (4 rows each)
  const int c   = l & 7;       // k-chunk 0..7 (64 ks)
  const int rg  = wvi * 8 + jj;  // WG row group 0..31

  // h_t staged as 8 chunks of 64 f16, chunk stride 144 B: reads at c*144+16q
  // tile all 32 banks across the 8 distinct c (broadcast within same-c lanes)
  // -> conflict-free ds_read_b128. Poll-writes: 2 lanes/bank = free.
  __shared__ __align__(16) unsigned char hmem[8 * 144];

  // ---- one-time: Wh rows 128g+4rg..+3, cols 64c..64c+63 -> 32 x f16x8 (128 VGPRs)
  f16x8 wreg[32];
#pragma unroll
  for (int i = 0; i < 4; ++i) {
    const float* wrow = W + (size_t)(128 * g + 4 * rg + i) * 1024 + 64 * c;
#pragma unroll
    for (int q = 0; q < 8; ++q) {
      float4 wa = *(const float4*)(wrow + 8 * q);
      float4 wb = *(const float4*)(wrow + 8 * q + 4);
      f16x8 p = {(_Float16)wa.x, (_Float16)wa.y, (_Float16)wa.z, (_Float16)wa.w,
                 (_Float16)wb.x, (_Float16)wb.y, (_Float16)wb.z, (_Float16)wb.w};
      wreg[i * 8 + q] = p;
    }
  }

  const unsigned int* ubase = (const unsigned int*)U;
  unsigned long long* hb = hbuf + (size_t)batch * 256;  // parity stride NB*256

  const bool puber = (c < 2);
  const int wpub = 2 * rg + c;        // word within WG slice (publishers)
  const int wid  = g * 64 + wpub;     // global word 0..255

  float h0f = 0.f, h1f = 0.f;
  for (int t = 0; t < SEQ; ++t) {
    // prefetch this step's U word (publishers; independent of sync)
    unsigned int ubits = 0;
    if (puber)
      ubits = ubase[((size_t)t * NB + batch) * 256 + wid];

    // poll my h word for tag t (parity t&1); tag+data are one atomic u64
    {
      const unsigned long long* src = hb + (size_t)(t & 1) * (NB * 256) + tid;
      unsigned long long e;
      do {
        e = __hip_atomic_load(src, __ATOMIC_RELAXED, __HIP_MEMORY_SCOPE_AGENT);
      } while ((unsigned int)(e >> 32) != (unsigned int)t);
      *(unsigned int*)(hmem + (tid >> 5) * 144 + (tid & 31) * 4) = (unsigned int)e;
    }
    __syncthreads();  // SYNC1: h_t staged WG-wide

    // 4 rows x 64 ks from VGPR-resident weights: 8 ds_read_b128 + 128 v_dot2
    float a[4] = {0.f, 0.f, 0.f, 0.f};
    const unsigned char* hc = hmem + c * 144;
#pragma unroll
    for (int q = 0; q < 8; ++q) {
      f16x8 hv = *(const f16x8*)(hc + 16 * q);
      half2v h0 = {hv[0], hv[1]}, h1 = {hv[2], hv[3]},
             h2 = {hv[4], hv[5]}, h3 = {hv[6], hv[7]};
#pragma unroll
      for (int i = 0; i < 4; ++i) {
        f16x8 wv = wreg[i * 8 + q];
        half2v w0 = {wv[0], wv[1]}, w1 = {wv[2], wv[3]},
               w2 = {wv[4], wv[5]}, w3 = {wv[6], wv[7]};
        a[i] = DOT2(w0, h0, a[i]);
        a[i] = DOT2(w1, h1, a[i]);
        a[i] = DOT2(w2, h2, a[i]);
        a[i] = DOT2(w3, h3, a[i]);
      }
    }
    // butterfly over the 8 k-chunks (partials live in lanes differing in bits 0..2)
#pragma unroll
    for (int m = 1; m <= 4; m <<= 1) {
#pragma unroll
      for (int i = 0; i < 4; ++i) a[i] += __shfl_xor(a[i], m, 64);
    }

    // publish BEFORE SYNC2: publish(t+1) follows SYNC1(t) in program order,
    // which proves all remote slices reached tag t, which proves every remote
    // WG finished reading tag t-1 from the slot being overwritten.
    if (puber) {
      half2v uh = __builtin_bit_cast(half2v, ubits);
      float s0 = (c == 0) ? a[0] : a[2];
      float s1 = (c == 0) ? a[1] : a[3];
      h0f = fast_tanh(s0 + (float)uh.x);
      h1f = fast_tanh(s1 + (float)uh.y);
      half2v hh;
      hh.x = (_Float16)h0f;
      hh.y = (_Float16)h1f;
      unsigned long long word =
          ((unsigned long long)(unsigned int)(t + 1) << 32) |
          (unsigned long long)__builtin_bit_cast(unsigned int, hh);
      __hip_atomic_store(hb + (size_t)((t + 1) & 1) * (NB * 256) + wid, word,
                         __ATOMIC_RELAXED, __HIP_MEMORY_SCOPE_AGENT);
    }
    __syncthreads();  // SYNC2: all iter-t hmem reads done before t+1 poll-writes
  }
  if (puber) {
    out[(size_t)batch * HID + 128 * g + 2 * wpub]     = h0f;
    out[(size_t)batch * HID + 128 * g + 2 * wpub + 1] = h1f;
  }
}

// ------------------------------------------------------------------- host ---
extern "C" void kernel_launch(void* const* d_in, const int* in_sizes, int n_in,
                              void* d_out, int out_size, void* d_ws, size_t ws_size,
                              hipStream_t stream) {
  const float* X    = (const float*)d_in[0];  // [1024][64][512]
  const float* W    = (const float*)d_in[1];  // [512][1024]
  const float* bias = (const float*)d_in[2];  // [512]
  float* out = (float*)d_out;                 // [64][512]

  // ws layout: U f16 (64 MiB) | hbuf u64[2][64][256] (256 KiB)
  char* ws = (char*)d_ws;
  _Float16* U = (_Float16*)ws;
  unsigned long long* hbuf =
      (unsigned long long*)(ws + (size_t)SEQ * NB * HID * 2);

  // parity-0 buffer = h_0 = 0 with tag 0 (ws is re-poisoned 0xAA each call;
  // 0xAAAAAAAA can never equal a tag in [0,1024], so parity-1 needs no init)
  hipMemsetAsync(hbuf, 0, (size_t)NB * 256 * 8, stream);

  rnn_prepass<<<dim3(512, 4), dim3(256), 0, stream>>>(X, W, bias, U);

  const float* Wp = W;
  const _Float16* Up = U;
  unsigned long long* hb = hbuf;
  float* op = out;
  void* args[] = {(void*)&Wp, (void*)&Up, (void*)&hb, (void*)&op};
  // cooperative launch: all 256 spinning WGs co-resident (1 WG/CU)
  hipError_t e = hipLaunchCooperativeKernel(
      reinterpret_cast<void*>(rnn_recur), dim3(256), dim3(256), args, 0, stream);
  if (e != hipSuccess) {
    rnn_recur<<<dim3(256), dim3(256), 0, stream>>>(Wp, Up, hb, op);
  }
}